// Round 1
// baseline (261.734 us; speedup 1.0000x reference)
//
#include <hip/hip_runtime.h>
#include <stdint.h>

#define BATCH 4096
#define IN_DIM 1024
#define HID 1024
#define KDIM 2048      // IN + HID
#define NGATE 4096     // 4 * HID

typedef __attribute__((ext_vector_type(4))) float floatx4;
typedef __attribute__((ext_vector_type(8))) __bf16 bf16x8;

__device__ __forceinline__ unsigned short f2bf(float f) {
    union { float f; unsigned int u; } v; v.f = f;
    unsigned int u = v.u;
    u += 0x7fffu + ((u >> 16) & 1u);   // RNE; inputs finite
    return (unsigned short)(u >> 16);
}
__device__ __forceinline__ float bf2f(unsigned short s) {
    union { unsigned int u; float f; } v; v.u = ((unsigned int)s) << 16;
    return v.f;
}

// ---------------------------------------------------------------------------
// prep: X = [x | h] as bf16 (4096 x 2048); W = gate-major [w_g_i | w_g_h] as
// bf16 (4096 x 2048, row n = gate*1024+hid, B^T form); bias[n] = b_i + b_h.
// ---------------------------------------------------------------------------
__global__ void prep_kernel(
    const float* __restrict__ x,  const float* __restrict__ h,
    const float* __restrict__ wii, const float* __restrict__ wih,
    const float* __restrict__ wfi, const float* __restrict__ wfh,
    const float* __restrict__ wgi, const float* __restrict__ wgh,
    const float* __restrict__ woi, const float* __restrict__ woh,
    const float* __restrict__ bii, const float* __restrict__ bih,
    const float* __restrict__ bfi, const float* __restrict__ bfh,
    const float* __restrict__ bgi, const float* __restrict__ bgh,
    const float* __restrict__ boi, const float* __restrict__ boh,
    unsigned short* __restrict__ Xb,
    unsigned short* __restrict__ Wb,
    float* __restrict__ bias)
{
    const int t = blockIdx.x * blockDim.x + threadIdx.x;   // one float4 chunk
    const int XV = BATCH * KDIM / 4;                        // 2M chunks for X
    if (t < XV) {
        const int e = t * 4;
        const int b = e >> 11, k = e & 2047;
        const float* src = (k < IN_DIM) ? (x + (size_t)b * IN_DIM + k)
                                        : (h + (size_t)b * HID + (k - IN_DIM));
        float4 v = *(const float4*)src;
        ushort4 o = { f2bf(v.x), f2bf(v.y), f2bf(v.z), f2bf(v.w) };
        *(ushort4*)(Xb + e) = o;
    } else if (t < 2 * XV) {
        const int e = (t - XV) * 4;
        const int r = e >> 11, k = e & 2047;
        const int gate = r >> 10, n = r & 1023;
        const float* wi_[4] = { wii, wfi, wgi, woi };
        const float* wh_[4] = { wih, wfh, wgh, woh };
        const float* src = (k < IN_DIM) ? (wi_[gate] + (size_t)n * IN_DIM + k)
                                        : (wh_[gate] + (size_t)n * HID + (k - IN_DIM));
        float4 v = *(const float4*)src;
        ushort4 o = { f2bf(v.x), f2bf(v.y), f2bf(v.z), f2bf(v.w) };
        *(ushort4*)(Wb + e) = o;
    }
    if (t < NGATE) {
        const int gate = t >> 10, n = t & 1023;
        const float* bi_[4] = { bii, bfi, bgi, boi };
        const float* bh_[4] = { bih, bfh, bgh, boh };
        bias[t] = bi_[gate][n] + bh_[gate][n];
    }
}

// ---------------------------------------------------------------------------
// gemm_gates: C[m][n] = act( sum_k X[m][k]*W[n][k] + bias[n] )
// 128x128 tile, BK=32, 256 threads (4 waves, each 64x64 = 4x4 MFMA tiles).
// global_load_lds width-16 staging (LDS dest = wave base + lane*16 — layout
// must be flat-contiguous, NO padding).
// ---------------------------------------------------------------------------
#define GLD16(g, l)                                                          \
    __builtin_amdgcn_global_load_lds(                                        \
        (__attribute__((address_space(1))) void*)(g),                        \
        (__attribute__((address_space(3))) void*)(l), 16, 0, 0)

__global__ __launch_bounds__(256) void gemm_gates(
    const unsigned short* __restrict__ X,
    const unsigned short* __restrict__ W,
    const float* __restrict__ bias,
    unsigned short* __restrict__ G)
{
    __shared__ __align__(16) unsigned short As[128 * 32];
    __shared__ __align__(16) unsigned short Bs[128 * 32];

    const int tid  = threadIdx.x;
    const int wave = tid >> 6;
    const int lane = tid & 63;
    const int quad = lane >> 4, idx = lane & 15;
    const int wm = (wave >> 1) * 64, wn = (wave & 1) * 64;

    const int rowA0 = blockIdx.x * 128;
    const int rowB0 = blockIdx.y * 128;

    // staging round r in {0,1}: flat chunk f = r*256 + tid; row=f>>2, k=(f&3)*8
    const int srow = tid >> 2, skk = (tid & 3) * 8;
    const unsigned short* gA0 = X + (size_t)(rowA0 + srow) * KDIM + skk;
    const unsigned short* gA1 = X + (size_t)(rowA0 + 64 + srow) * KDIM + skk;
    const unsigned short* gB0 = W + (size_t)(rowB0 + srow) * KDIM + skk;
    const unsigned short* gB1 = W + (size_t)(rowB0 + 64 + srow) * KDIM + skk;

    floatx4 acc[4][4] = {};

    for (int k0 = 0; k0 < KDIM; k0 += 32) {
        GLD16(gA0 + k0, As + tid * 8);
        GLD16(gA1 + k0, As + 2048 + tid * 8);
        GLD16(gB0 + k0, Bs + tid * 8);
        GLD16(gB1 + k0, Bs + 2048 + tid * 8);
        __syncthreads();

        bf16x8 af[4], bfr[4];
#pragma unroll
        for (int i = 0; i < 4; ++i)
            af[i] = *(const bf16x8*)(As + (wm + i * 16 + idx) * 32 + quad * 8);
#pragma unroll
        for (int j = 0; j < 4; ++j)
            bfr[j] = *(const bf16x8*)(Bs + (wn + j * 16 + idx) * 32 + quad * 8);
#pragma unroll
        for (int i = 0; i < 4; ++i)
#pragma unroll
            for (int j = 0; j < 4; ++j)
                acc[i][j] = __builtin_amdgcn_mfma_f32_16x16x32_bf16(
                    af[i], bfr[j], acc[i][j], 0, 0, 0);
        __syncthreads();
    }

    // epilogue: bias + activation, store activated gate as bf16
#pragma unroll
    for (int j = 0; j < 4; ++j) {
        const int col = rowB0 + wn + j * 16 + idx;
        const float bv = bias[col];
        const int gate = col >> 10;            // tile is 16-aligned: wave-uniform
#pragma unroll
        for (int i = 0; i < 4; ++i) {
#pragma unroll
            for (int r = 0; r < 4; ++r) {
                const int row = rowA0 + wm + i * 16 + quad * 4 + r;
                const float v = acc[i][j][r] + bv;
                float a;
                if (gate == 2) {               // g-gate: tanh
                    const float e = __expf(2.f * v);
                    a = (e - 1.f) / (e + 1.f);
                } else {                       // i,f,o: sigmoid
                    a = 1.f / (1.f + __expf(-v));
                }
                G[(size_t)row * NGATE + col] = f2bf(a);
            }
        }
    }
}

// ---------------------------------------------------------------------------
// ew: c' = f*c + i*g ; h' = o*tanh(c') ; out = [h' (4M) | c' (4M)] fp32
// ---------------------------------------------------------------------------
__global__ void ew_kernel(const unsigned short* __restrict__ G,
                          const float* __restrict__ c,
                          float* __restrict__ out)
{
    const int t = blockIdx.x * blockDim.x + threadIdx.x;   // 0 .. 4M-1
    const int b = t >> 10, n = t & 1023;
    const unsigned short* g = G + (size_t)b * NGATE;
    const float iv = bf2f(g[n]);
    const float fv = bf2f(g[HID + n]);
    const float gv = bf2f(g[2 * HID + n]);
    const float ov = bf2f(g[3 * HID + n]);
    const float cv = c[t];
    const float cp = fv * cv + iv * gv;
    const float e  = __expf(2.f * cp);
    const float th = (e - 1.f) / (e + 1.f);
    out[t] = ov * th;
    out[(size_t)BATCH * HID + t] = cp;
}

// ---------------------------------------------------------------------------
extern "C" void kernel_launch(void* const* d_in, const int* in_sizes, int n_in,
                              void* d_out, int out_size, void* d_ws, size_t ws_size,
                              hipStream_t stream) {
    const float* x   = (const float*)d_in[0];
    const float* h   = (const float*)d_in[1];
    const float* c   = (const float*)d_in[2];
    const float* wii = (const float*)d_in[3];
    const float* bii = (const float*)d_in[4];
    const float* wih = (const float*)d_in[5];
    const float* bih = (const float*)d_in[6];
    const float* wfi = (const float*)d_in[7];
    const float* bfi = (const float*)d_in[8];
    const float* wfh = (const float*)d_in[9];
    const float* bfh = (const float*)d_in[10];
    const float* wgi = (const float*)d_in[11];
    const float* bgi = (const float*)d_in[12];
    const float* wgh = (const float*)d_in[13];
    const float* bgh = (const float*)d_in[14];
    const float* woi = (const float*)d_in[15];
    const float* boi = (const float*)d_in[16];
    const float* woh = (const float*)d_in[17];
    const float* boh = (const float*)d_in[18];

    char* ws = (char*)d_ws;
    unsigned short* Xb  = (unsigned short*)ws;                                // 16 MB
    unsigned short* Wb  = (unsigned short*)(ws + ((size_t)16 << 20));         // 16 MB
    float*          bsv = (float*)(ws + ((size_t)32 << 20));                  // 16 KB
    unsigned short* G   = (unsigned short*)(ws + ((size_t)32 << 20) + 65536); // 32 MB

    const int prep_threads = 2 * BATCH * KDIM / 4;  // 4M
    prep_kernel<<<(prep_threads + 255) / 256, 256, 0, stream>>>(
        x, h, wii, wih, wfi, wfh, wgi, wgh, woi, woh,
        bii, bih, bfi, bfh, bgi, bgh, boi, boh, Xb, Wb, bsv);

    dim3 g2(BATCH / 128, NGATE / 128);
    gemm_gates<<<g2, 256, 0, stream>>>(Xb, Wb, bsv, G);

    ew_kernel<<<(BATCH * HID + 255) / 256, 256, 0, stream>>>(G, c, (float*)d_out);
}